// Round 1
// baseline (400.087 us; speedup 1.0000x reference)
//
#include <hip/hip_runtime.h>
#include <math.h>

// Round 6: attn_fused stats-phase overhaul.
//  - softmax stats read scores as bf8 vectors (ds_read_b128), kept in regs
//  - cross-part reduction via __shfl_xor (8 lanes/row), zero syncthreads
//  - packed scores written as coalesced 16B stores from stats (not scalar u16)
//  - mask staged in padded mk[8][68] layout (odd granule stride, no conflicts)
//  - Q fragments hoisted out of the Phase-A s-tile loop
//  - Phase B uses 64-wide V chunks (8 iters x 4 MFMA, half the barriers)
// Rest of the pipeline identical to round 5.

typedef short bf8 __attribute__((ext_vector_type(8)));
typedef float f32x4 __attribute__((ext_vector_type(4)));
typedef unsigned short u16;

constexpr int LDT = 40;  // LDS row stride in shorts (32 data + 8 pad)
enum { EPI_NONE = 0, EPI_BIAS_RELU = 1, EPI_BIAS = 2, EPI_RESID = 3 };
#define RSQRT2 0.70710678118654752f

__device__ __forceinline__ u16 f2bf(float f) {
  unsigned int u = __builtin_bit_cast(unsigned int, f);
  unsigned int r = u + 0x7fffu + ((u >> 16) & 1u);  // RNE
  return (u16)(r >> 16);
}
__device__ __forceinline__ float bf2f(u16 v) {
  return __builtin_bit_cast(float, (unsigned int)v << 16);
}
__device__ __forceinline__ f32x4 mfma16(bf8 a, bf8 b, f32x4 c) {
  return __builtin_amdgcn_mfma_f32_16x16x32_bf16(a, b, c, 0, 0, 0);
}

// ---------------- batched f32 -> bf16 conversion -----------------------------
struct CvtDesc { const float* src; u16* dst; int n; };
struct CvtArgs { CvtDesc d[8]; };

__global__ __launch_bounds__(256) void cvt_k(CvtArgs a) {
  CvtDesc d = a.d[blockIdx.z];
  int i = (blockIdx.x * 256 + threadIdx.x) * 8;
  if (i >= d.n) return;
  f32x4 v0 = *(const f32x4*)(d.src + i);
  f32x4 v1 = *(const f32x4*)(d.src + i + 4);
  bf8 o;
  o[0] = (short)f2bf(v0[0]); o[1] = (short)f2bf(v0[1]);
  o[2] = (short)f2bf(v0[2]); o[3] = (short)f2bf(v0[3]);
  o[4] = (short)f2bf(v1[0]); o[5] = (short)f2bf(v1[1]);
  o[6] = (short)f2bf(v1[2]); o[7] = (short)f2bf(v1[3]);
  *(bf8*)(d.dst + i) = o;
}

// ------- 128x64-tile bf16 GEMM: C[M,N] = A[M,K](bf16) @ B[N,K](bf16)^T ------
template <int EPI, bool BFOUT>
__global__ __launch_bounds__(256) void mgemm2(
    const u16* __restrict__ A, const u16* __restrict__ B,
    void* __restrict__ Cv, int M, int N, int K, int lda, int ldb, int ldc,
    const float* __restrict__ bias, const float* __restrict__ Hin,
    const int* __restrict__ gatherA, const int* __restrict__ scatterC) {
  __shared__ __align__(16) u16 As[128 * LDT];
  __shared__ __align__(16) u16 Bs[64 * LDT];
  const int tid = threadIdx.x;
  const int m0 = blockIdx.y * 128, n0 = blockIdx.x * 64;
  const int wave = tid >> 6, lane = tid & 63;
  const int wm = (wave & 1) * 64, wn = (wave >> 1) * 32;
  const int lrow = lane & 15, quad = lane >> 4;
  const int srow = tid >> 2, skq = tid & 3;

  int gr0 = m0 + srow, gr1 = m0 + srow + 64;
  int ar0 = (gr0 < M) ? (gatherA ? gatherA[gr0] : gr0) : -1;
  int ar1 = (gr1 < M) ? (gatherA ? gatherA[gr1] : gr1) : -1;
  const u16* Ap0 = (ar0 >= 0) ? A + (size_t)ar0 * lda + skq * 8 : nullptr;
  const u16* Ap1 = (ar1 >= 0) ? A + (size_t)ar1 * lda + skq * 8 : nullptr;
  const u16* Bp = (n0 + srow < N) ? B + (size_t)(n0 + srow) * ldb + skq * 8 : nullptr;
  u16* AsW0 = &As[srow * LDT + skq * 8];
  u16* AsW1 = &As[(srow + 64) * LDT + skq * 8];
  u16* BsW = &Bs[srow * LDT + skq * 8];

  f32x4 acc[4][2];
#pragma unroll
  for (int i = 0; i < 4; ++i)
#pragma unroll
    for (int j = 0; j < 2; ++j) acc[i][j] = (f32x4){0.f, 0.f, 0.f, 0.f};
  const bf8 z8 = {0, 0, 0, 0, 0, 0, 0, 0};

  for (int k0 = 0; k0 < K; k0 += 32) {
    bf8 a0 = Ap0 ? *(const bf8*)(Ap0 + k0) : z8;
    bf8 a1 = Ap1 ? *(const bf8*)(Ap1 + k0) : z8;
    bf8 bv = Bp ? *(const bf8*)(Bp + k0) : z8;
    *(bf8*)AsW0 = a0;
    *(bf8*)AsW1 = a1;
    *(bf8*)BsW = bv;
    __syncthreads();
    bf8 af[4], bfr[2];
#pragma unroll
    for (int i = 0; i < 4; ++i)
      af[i] = *(const bf8*)&As[(wm + i * 16 + lrow) * LDT + quad * 8];
#pragma unroll
    for (int j = 0; j < 2; ++j)
      bfr[j] = *(const bf8*)&Bs[(wn + j * 16 + lrow) * LDT + quad * 8];
#pragma unroll
    for (int i = 0; i < 4; ++i)
#pragma unroll
      for (int j = 0; j < 2; ++j) acc[i][j] = mfma16(af[i], bfr[j], acc[i][j]);
    __syncthreads();
  }

  float* Cf = (float*)Cv;
  u16* Cb = (u16*)Cv;
#pragma unroll
  for (int i = 0; i < 4; ++i) {
#pragma unroll
    for (int r = 0; r < 4; ++r) {
      int row = m0 + wm + i * 16 + quad * 4 + r;
      if (row >= M) continue;
      if (gatherA && gatherA[row] < 0) continue;
      int orow = scatterC ? scatterC[row] : row;
#pragma unroll
      for (int j = 0; j < 2; ++j) {
        int col = n0 + wn + j * 16 + lrow;
        if (col >= N) continue;
        float v = acc[i][j][r];
        if (EPI == EPI_BIAS_RELU) v = fmaxf(v + bias[col], 0.f);
        else if (EPI == EPI_BIAS) v += bias[col];
        else if (EPI == EPI_RESID) v = (Hin[(size_t)row * ldc + col] + v + bias[col]) * RSQRT2;
        if (BFOUT) Cb[(size_t)orow * ldc + col] = f2bf(v);
        else Cf[(size_t)orow * ldc + col] = v;
      }
    }
  }
}

// ---------------- old 64x64 fp32-input GEMM (head only, N=20) ----------------
template <int EPI>
__global__ __launch_bounds__(256) void mgemm(
    const float* __restrict__ A, const float* __restrict__ B,
    float* __restrict__ Cf, int M, int N, int K, int lda, int ldb, int ldc,
    const float* __restrict__ bias, const int* __restrict__ scatterC) {
  __shared__ __align__(16) u16 As[64 * LDT];
  __shared__ __align__(16) u16 Bs[64 * LDT];
  const int tid = threadIdx.x;
  const int m0 = blockIdx.y * 64, n0 = blockIdx.x * 64;
  const int wave = tid >> 6, lane = tid & 63;
  const int wm = (wave & 1) * 32, wn = (wave >> 1) * 32;
  const int lrow = lane & 15, quad = lane >> 4;
  const int srow = tid >> 2, skq = tid & 3;
  const float* Ap = (m0 + srow < M) ? A + (size_t)(m0 + srow) * lda + skq * 8 : nullptr;
  const float* Bp = (n0 + srow < N) ? B + (size_t)(n0 + srow) * ldb + skq * 8 : nullptr;
  u16* AsW = &As[srow * LDT + skq * 8];
  u16* BsW = &Bs[srow * LDT + skq * 8];
  const u16* Afr = &As[(wm + lrow) * LDT + quad * 8];
  const u16* Bfr = &Bs[(wn + lrow) * LDT + quad * 8];
  f32x4 acc00 = {0.f, 0.f, 0.f, 0.f}, acc01 = acc00, acc10 = acc00, acc11 = acc00;
  const bf8 z8 = {0, 0, 0, 0, 0, 0, 0, 0};
  for (int k0 = 0; k0 < K; k0 += 32) {
    bf8 av = z8, bv = z8;
    if (Ap) {
      f32x4 x0 = *(const f32x4*)(Ap + k0), x1 = *(const f32x4*)(Ap + k0 + 4);
#pragma unroll
      for (int j = 0; j < 4; ++j) { av[j] = (short)f2bf(x0[j]); av[j + 4] = (short)f2bf(x1[j]); }
    }
    if (Bp) {
      f32x4 x0 = *(const f32x4*)(Bp + k0), x1 = *(const f32x4*)(Bp + k0 + 4);
#pragma unroll
      for (int j = 0; j < 4; ++j) { bv[j] = (short)f2bf(x0[j]); bv[j + 4] = (short)f2bf(x1[j]); }
    }
    *(bf8*)AsW = av;
    *(bf8*)BsW = bv;
    __syncthreads();
    bf8 a0 = *(const bf8*)Afr;
    bf8 a1 = *(const bf8*)(Afr + 16 * LDT);
    bf8 b0 = *(const bf8*)Bfr;
    bf8 b1 = *(const bf8*)(Bfr + 16 * LDT);
    acc00 = mfma16(a0, b0, acc00);
    acc01 = mfma16(a0, b1, acc01);
    acc10 = mfma16(a1, b0, acc10);
    acc11 = mfma16(a1, b1, acc11);
    __syncthreads();
  }
#pragma unroll
  for (int mi = 0; mi < 2; ++mi) {
    f32x4 r0 = mi ? acc10 : acc00;
    f32x4 r1 = mi ? acc11 : acc01;
#pragma unroll
    for (int r = 0; r < 4; ++r) {
      int row = m0 + wm + mi * 16 + quad * 4 + r;
      if (row >= M) continue;
      int orow = scatterC ? scatterC[row] : row;
#pragma unroll
      for (int ni = 0; ni < 2; ++ni) {
        int col = n0 + wn + ni * 16 + lrow;
        if (col >= N) continue;
        float v = ni ? r1[r] : r0[r];
        if (EPI == EPI_BIAS) v += bias[col];
        Cf[(size_t)orow * ldc + col] = v;
      }
    }
  }
}

// ---------------- V transpose: KV[b][s][512+hd] -> VT[b][hd][s] (bf16) -------
__global__ __launch_bounds__(256) void vtrans(const u16* __restrict__ KV,
                                              u16* __restrict__ VT) {
  __shared__ u16 t[32][33];
  int b = blockIdx.z;
  int s0 = blockIdx.x * 32, d0 = blockIdx.y * 32;
  int tx = threadIdx.x & 31, ty = threadIdx.x >> 5;
#pragma unroll
  for (int i = 0; i < 32; i += 8)
    t[ty + i][tx] = KV[(size_t)(b * 512 + s0 + ty + i) * 1024 + 512 + d0 + tx];
  __syncthreads();
#pragma unroll
  for (int i = 0; i < 32; i += 8)
    VT[(size_t)(b * 512 + d0 + ty + i) * 512 + s0 + tx] = t[tx][ty + i];
}

// ---------------- fused attention: per (b,h,mtile32) -------------------------
// Phase A: scores 32m x 512s (K=64) -> LDS Ws (bf16).
// Stats: vectorized (bf8) per-row max / masked-sum; shfl_xor reduce over the
//   8 lanes of each row; packed global written as coalesced 16B stores.
// Phase B: feat 32m x 64d = W(32x512) @ VT(64x512)^T, 64-wide s chunks.
constexpr int WST = 520;  // W row stride (512 + 8 pad) -> 65 granules (odd)
constexpr int QST = 72;   // Q/K/V row stride (64 + 8 pad) -> 9 granules (odd)

__global__ __launch_bounds__(256) void attn_fused(
    const u16* __restrict__ Q, const u16* __restrict__ KV,
    const u16* __restrict__ VT, const int* __restrict__ list,
    const float* __restrict__ mask, u16* __restrict__ packed,
    u16* __restrict__ feat, int N) {
  const int b = blockIdx.y >> 3, h = blockIdx.y & 7;
  const int mt = blockIdx.x;
  const int* lst = list + (size_t)b * N + mt * 32;
  if (lst[0] < 0) return;

  __shared__ __align__(16) u16 Ws[32 * WST];
  __shared__ __align__(16) u16 Qs[32 * QST];
  __shared__ __align__(16) u16 KVs[64 * QST];  // K tiles (A) / V chunks (B)
  __shared__ __align__(16) float mk[8][68];    // mask, padded (17 granules/row)
  __shared__ int mS[32];

  const int tid = threadIdx.x;
  const int wave = tid >> 6, lane = tid & 63;
  const int wm = (wave & 1) * 16, wns = (wave >> 1) * 32;
  const int lrow = lane & 15, quad = lane >> 4;
  const bf8 z8 = {0, 0, 0, 0, 0, 0, 0, 0};

  if (tid < 32) mS[tid] = lst[tid];
  {  // stage mask into padded layout (float2 per thread)
    int p = tid >> 5, j = (tid & 31) * 2;
    *(float2*)&mk[p][j] = *(const float2*)&mask[(size_t)b * 512 + p * 64 + j];
  }
  {  // stage Q tile: 32 rows x 64k
    int qr = tid >> 3, kq = tid & 7;
    int m = lst[qr];
    *(bf8*)&Qs[qr * QST + kq * 8] =
        (m >= 0) ? *(const bf8*)(Q + (size_t)m * 512 + h * 64 + kq * 8) : z8;
  }
  __syncthreads();

  // Q fragments are s-tile-invariant: hoist out of the Phase-A loop.
  const bf8 qa0 = *(const bf8*)&Qs[(wm + lrow) * QST + 0 + quad * 8];
  const bf8 qa1 = *(const bf8*)&Qs[(wm + lrow) * QST + 32 + quad * 8];

  // ---- Phase A: scores ----
  const u16* KVb = KV + (size_t)(b * 512) * 1024 + h * 64;
  for (int st = 0; st < 8; ++st) {
#pragma unroll
    for (int i = 0; i < 2; ++i) {  // stage K tile: 64 rows x 64k
      int c = tid * 2 + i;
      int sr = c >> 3, kq = c & 7;
      *(bf8*)&KVs[sr * QST + kq * 8] =
          *(const bf8*)(KVb + (size_t)(st * 64 + sr) * 1024 + kq * 8);
    }
    __syncthreads();
    f32x4 acc0 = {0.f, 0.f, 0.f, 0.f}, acc1 = acc0;
    {
      bf8 b00 = *(const bf8*)&KVs[(wns + lrow) * QST + quad * 8];
      bf8 b10 = *(const bf8*)&KVs[(wns + 16 + lrow) * QST + quad * 8];
      bf8 b01 = *(const bf8*)&KVs[(wns + lrow) * QST + 32 + quad * 8];
      bf8 b11 = *(const bf8*)&KVs[(wns + 16 + lrow) * QST + 32 + quad * 8];
      acc0 = mfma16(qa0, b00, acc0);
      acc1 = mfma16(qa0, b10, acc1);
      acc0 = mfma16(qa1, b01, acc0);
      acc1 = mfma16(qa1, b11, acc1);
    }
#pragma unroll
    for (int r = 0; r < 4; ++r) {
      int lr = wm + quad * 4 + r;
      Ws[lr * WST + st * 64 + wns + lrow] = f2bf(acc0[r] * 0.125f);
      Ws[lr * WST + st * 64 + wns + 16 + lrow] = f2bf(acc1[r] * 0.125f);
    }
    __syncthreads();
  }

  // ---- Stats + W rebuild: 8 lanes per row, vectorized, shfl reductions ----
  {
    const int row = tid >> 3, part = tid & 7;
    u16* wrow = &Ws[row * WST + part * 64];
    const int mm = mS[row];
    bf8 w[8];
    float mx = -1e30f;
#pragma unroll
    for (int v = 0; v < 8; ++v) {
      w[v] = *(const bf8*)(wrow + v * 8);
#pragma unroll
      for (int j = 0; j < 8; ++j) mx = fmaxf(mx, bf2f((u16)w[v][j]));
    }
    if (mm >= 0) {  // packed raw scores, 16B coalesced stores
      u16* prow = packed + ((size_t)h * N + mm) * 512 + part * 64;
#pragma unroll
      for (int v = 0; v < 8; ++v) *(bf8*)(prow + v * 8) = w[v];
    }
#pragma unroll
    for (int d = 1; d < 8; d <<= 1) mx = fmaxf(mx, __shfl_xor(mx, d));
    float se = 0.f, ms = 0.f;
#pragma unroll
    for (int v = 0; v < 8; ++v) {
      f32x4 m0 = *(const f32x4*)&mk[part][v * 8];
      f32x4 m1 = *(const f32x4*)&mk[part][v * 8 + 4];
#pragma unroll
      for (int j = 0; j < 8; ++j) {
        float e = __expf(bf2f((u16)w[v][j]) - mx);
        se += e;
        ms += e * (j < 4 ? m0[j] : m1[j - 4]);
      }
    }
#pragma unroll
    for (int d = 1; d < 8; d <<= 1) {
      se += __shfl_xor(se, d);
      ms += __shfl_xor(ms, d);
    }
    float iv = 1.0f / (ms + 1e-6f * se);
#pragma unroll
    for (int v = 0; v < 8; ++v) {
      f32x4 m0 = *(const f32x4*)&mk[part][v * 8];
      f32x4 m1 = *(const f32x4*)&mk[part][v * 8 + 4];
      bf8 o;
#pragma unroll
      for (int j = 0; j < 8; ++j) {
        float e = __expf(bf2f((u16)w[v][j]) - mx);
        o[j] = (short)f2bf(e * (j < 4 ? m0[j] : m1[j - 4]) * iv);
      }
      *(bf8*)(wrow + v * 8) = o;
    }
  }
  __syncthreads();

  // ---- Phase B: feat = W @ VT^T  (32m x 64d, K=512), 64-wide s chunks ----
  f32x4 acc0 = {0.f, 0.f, 0.f, 0.f}, acc1 = acc0;
  const u16* VTb = VT + (size_t)(b * 512 + h * 64) * 512;
  for (int s0 = 0; s0 < 512; s0 += 64) {
#pragma unroll
    for (int i = 0; i < 2; ++i) {  // stage V chunk: 64 d-rows x 64 s
      int c = tid * 2 + i;
      int sr = c >> 3, kq = c & 7;
      *(bf8*)&KVs[sr * QST + kq * 8] =
          *(const bf8*)(VTb + (size_t)sr * 512 + s0 + kq * 8);
    }
    __syncthreads();
#pragma unroll
    for (int k0 = 0; k0 < 64; k0 += 32) {
      bf8 a = *(const bf8*)&Ws[(wm + lrow) * WST + s0 + k0 + quad * 8];
      bf8 b0 = *(const bf8*)&KVs[(wns + lrow) * QST + k0 + quad * 8];
      bf8 b1 = *(const bf8*)&KVs[(wns + 16 + lrow) * QST + k0 + quad * 8];
      acc0 = mfma16(a, b0, acc0);
      acc1 = mfma16(a, b1, acc1);
    }
    __syncthreads();
  }
#pragma unroll
  for (int r = 0; r < 4; ++r) {
    int lr = wm + quad * 4 + r;
    int mm = mS[lr];
    if (mm < 0) continue;
    u16* frow = feat + (size_t)mm * 512 + h * 64;
    frow[wns + lrow] = f2bf(acc0[r]);
    frow[wns + 16 + lrow] = f2bf(acc1[r]);
  }
}

// ---------------- unpack: packed[h][m][s] -> out_sc[pm[m]][s][h] fp32 --------
__global__ __launch_bounds__(256) void unpack_k(const u16* __restrict__ packed,
                                                const int* __restrict__ pm,
                                                float* __restrict__ out_sc,
                                                int N) {
  __shared__ u16 Ls[8 * 520];
  int m = blockIdx.x, tid = threadIdx.x;
  int h = tid >> 5, c = (tid & 31) * 16;
  const u16* row = packed + ((size_t)h * N + m) * 512 + c;
  *(bf8*)&Ls[h * 520 + c] = *(const bf8*)row;
  *(bf8*)&Ls[h * 520 + c + 8] = *(const bf8*)(row + 8);
  __syncthreads();
  float* orow = out_sc + (size_t)pm[m] * 4096;
#pragma unroll
  for (int i = 0; i < 16; ++i) {
    int e = tid + i * 256;
    orow[e] = bf2f(Ls[(e & 7) * 520 + (e >> 3)]);
  }
}

// ---------------- LayerNorm over W, eps=1e-5 ---------------------------------
template <int W, bool BFIN, bool BFOUT>
__global__ __launch_bounds__(256) void ln_k(const void* __restrict__ in,
                                            void* __restrict__ out,
                                            const float* __restrict__ g,
                                            const float* __restrict__ bb) {
  constexpr int PT = W / 256;
  __shared__ float red[256];
  int row = blockIdx.x, tid = threadIdx.x;
  float v[PT];
  float s = 0.f, sq = 0.f;
#pragma unroll
  for (int p = 0; p < PT; ++p) {
    int c = tid + p * 256;
    v[p] = BFIN ? bf2f(((const u16*)in)[(size_t)row * W + c])
                : ((const float*)in)[(size_t)row * W + c];
    s += v[p];
    sq += v[p] * v[p];
  }
  red[tid] = s;
  __syncthreads();
  for (int off = 128; off; off >>= 1) {
    if (tid < off) red[tid] += red[tid + off];
    __syncthreads();
  }
  float mean = red[0] * (1.0f / W);
  __syncthreads();
  red[tid] = sq;
  __syncthreads();
  for (int off = 128; off; off >>= 1) {
    if (tid < off) red[tid] += red[tid + off];
    __syncthreads();
  }
  float var = red[0] * (1.0f / W) - mean * mean;
  float is = 1.0f / sqrtf(var + 1e-5f);
#pragma unroll
  for (int p = 0; p < PT; ++p) {
    int c = tid + p * 256;
    float o = (v[p] - mean) * is * g[c] + bb[c];
    if (BFOUT) ((u16*)out)[(size_t)row * W + c] = f2bf(o);
    else ((float*)out)[(size_t)row * W + c] = o;
  }
}

// ---------------- final: out_x = LN(x + scatter(ag)/sqrt2) -------------------
__global__ __launch_bounds__(256) void outx_k(
    const float* __restrict__ x, const float* __restrict__ ag,
    const int* __restrict__ inv, const float* __restrict__ g,
    const float* __restrict__ bb, float* __restrict__ out) {
  __shared__ float red[256];
  int n = blockIdx.x, tid = threadIdx.x;
  int mi = inv[n];
  float v = x[(size_t)n * 256 + tid];
  if (mi >= 0) v += ag[(size_t)mi * 256 + tid] * RSQRT2;
  red[tid] = v;
  __syncthreads();
  for (int off = 128; off; off >>= 1) {
    if (tid < off) red[tid] += red[tid + off];
    __syncthreads();
  }
  float mean = red[0] * (1.0f / 256.0f);
  __syncthreads();
  red[tid] = v * v;
  __syncthreads();
  for (int off = 128; off; off >>= 1) {
    if (tid < off) red[tid] += red[tid + off];
    __syncthreads();
  }
  float var = red[0] * (1.0f / 256.0f) - mean * mean;
  float is = 1.0f / sqrtf(var + 1e-5f);
  out[(size_t)n * 256 + tid] = (v - mean) * is * g[tid] + bb[tid];
}

// ---------------- index compaction -------------------------------------------
__global__ void init_idx_k(int* __restrict__ list, int* __restrict__ inv,
                           int* __restrict__ cnt, int N, int B) {
  int i = blockIdx.x * 256 + threadIdx.x;
  if (i < B * N) list[i] = -1;
  if (i < N) inv[i] = -1;
  if (i < B) cnt[i] = 0;
}

__global__ void compact_k(const int* __restrict__ pm,
                          const int* __restrict__ batch, int* __restrict__ list,
                          int* __restrict__ inv, int* __restrict__ cnt, int N) {
  int m = blockIdx.x * 256 + threadIdx.x;
  if (m >= N) return;
  int p = pm[m];
  int b = batch[p];
  int slot = atomicAdd(&cnt[b], 1);
  list[(size_t)b * N + slot] = m;
  inv[p] = m;
}

// -----------------------------------------------------------------------------
extern "C" void kernel_launch(void* const* d_in, const int* in_sizes, int n_in,
                              void* d_out, int out_size, void* d_ws,
                              size_t ws_size, hipStream_t stream) {
  const float* x = (const float*)d_in[0];
  const float* emb = (const float*)d_in[1];
  const float* mask = (const float*)d_in[2];
  const int* pm = (const int*)d_in[3];
  const int* batch = (const int*)d_in[4];
  const float* Wq = (const float*)d_in[5];
  const float* Wk = (const float*)d_in[6];
  const float* Wv = (const float*)d_in[7];
  const float* ag_s = (const float*)d_in[8];
  const float* ag_b = (const float*)d_in[9];
  const float* Wag = (const float*)d_in[10];
  const float* rls = (const float*)d_in[11];
  const float* rlb = (const float*)d_in[12];
  const float* rw1 = (const float*)d_in[13];
  const float* rb1 = (const float*)d_in[14];
  const float* rw2 = (const float*)d_in[15];
  const float* rb2 = (const float*)d_in[16];
  const float* hw = (const float*)d_in[17];
  const float* hb = (const float*)d_in[18];
  const float* ens = (const float*)d_in[19];
  const float* enb = (const float*)d_in[20];

  const int N = in_sizes[0] / 256;  // 4096
  const int B = in_sizes[2] / 512;  // 4

  char* wsb = (char*)d_ws;
  // conversion-phase (dead before packed is written):
  u16* embbf = (u16*)(wsb + 0);
  u16* xbf   = (u16*)(wsb + 5242880);
  u16* Wkvbf = (u16*)(wsb + 7340032);
  u16* Wqbf  = (u16*)(wsb + 9961472);
  // attention phase:
  u16* packed = (u16*)(wsb + 0);           // 32 MB
  u16* KVbf   = (u16*)(wsb + 33554432);    // 4 MB
  u16* Qbf    = (u16*)(wsb + 37748736);    // 4 MB
  u16* VT     = (u16*)(wsb + 41943040);    // 2 MB
  u16* featE  = (u16*)(wsb + 44040192);    // 4 MB
  // post-attention (aliases onto dead buffers):
  u16* LNF = (u16*)(wsb + 33554432);       // over KVbf
  float* AG = (float*)(wsb + 37748736);    // over Qbf
  u16* LNb = (u16*)(wsb + 0);              // over packed (dead after unpack)
  u16* Tb  = (u16*)(wsb + 2097152);
  float* Hb = (float*)(wsb + 4194304);
  // persistent:
  u16* Wagbf = (u16*)(wsb + 48234496);
  u16* rw1bf = (u16*)(wsb + 48496640);
  u16* rw2bf = (u16*)(wsb + 48889856);
  int* list  = (int*)(wsb + 49545216);
  int* inv   = (int*)(wsb + 49610752);
  int* cnt   = (int*)(wsb + 49627136);

  float* out_x = (float*)d_out;
  float* out_lg = out_x + (size_t)N * 256;
  float* out_sc = out_lg + (size_t)N * 20;

  // 0. conversions + index compaction
  CvtArgs ca;
  ca.d[0] = {emb, embbf, 2 * 512 * 1280 * 2};
  ca.d[1] = {x, xbf, 4096 * 256};
  ca.d[2] = {Wk, Wkvbf, 512 * 1280};
  ca.d[3] = {Wv, Wkvbf + 512 * 1280, 512 * 1280};
  ca.d[4] = {Wq, Wqbf, 512 * 256};
  ca.d[5] = {Wag, Wagbf, 256 * 512};
  ca.d[6] = {rw1, rw1bf, 3 * 256 * 256};
  ca.d[7] = {rw2, rw2bf, 3 * 256 * 256};
  cvt_k<<<dim3(1281, 1, 8), 256, 0, stream>>>(ca);
  init_idx_k<<<(B * N + 255) / 256, 256, 0, stream>>>(list, inv, cnt, N, B);
  compact_k<<<(N + 255) / 256, 256, 0, stream>>>(pm, batch, list, inv, cnt, N);

  // 1. fused K+V projection
  mgemm2<EPI_NONE, true><<<dim3(16, 16), 256, 0, stream>>>(
      embbf, Wkvbf, KVbf, B * 512, 1024, 1280, 1280, 1280, 1024,
      nullptr, nullptr, nullptr, nullptr);
  // 2. Q projection with gather
  mgemm2<EPI_NONE, true><<<dim3(8, 32), 256, 0, stream>>>(
      xbf, Wqbf, Qbf, N, 512, 256, 256, 256, 512,
      nullptr, nullptr, pm, nullptr);
  vtrans<<<dim3(16, 16, B), 256, 0, stream>>>(KVbf, VT);

  // 3. fused attention (scores+softmax+PV), then unpack for the fp32 output
  attn_fused<<<dim3(N / 32, B * 8), 256, 0, stream>>>(
      Qbf, KVbf, VT, list, mask, packed, featE, N);
  unpack_k<<<N, 256, 0, stream>>>(packed, pm, out_sc, N);

  // 4. ag = LN(feat) @ Wag^T
  ln_k<512, true, true><<<N, 256, 0, stream>>>(featE, LNF, ag_s, ag_b);
  mgemm2<EPI_NONE, false><<<dim3(4, 32), 256, 0, stream>>>(
      LNF, Wagbf, AG, N, 256, 512, 512, 512, 256,
      nullptr, nullptr, nullptr, nullptr);

  // 5. residual MLP
  const float* hin = AG;
  for (int i = 0; i < 3; ++i) {
    ln_k<256, false, true><<<N, 256, 0, stream>>>(hin, LNb, rls + i * 256, rlb + i * 256);
    mgemm2<EPI_BIAS_RELU, true><<<dim3(4, 32), 256, 0, stream>>>(
        LNb, rw1bf + (size_t)i * 65536, Tb, N, 256, 256, 256, 256, 256,
        rb1 + i * 256, nullptr, nullptr, nullptr);
    mgemm2<EPI_RESID, false><<<dim3(4, 32), 256, 0, stream>>>(
        Tb, rw2bf + (size_t)i * 65536, Hb, N, 256, 256, 256, 256, 256,
        rb2 + i * 256, hin, nullptr, nullptr);
    hin = Hb;
  }
  // 6. head (scatter to pm rows)
  mgemm<EPI_BIAS><<<dim3(1, 64), 256, 0, stream>>>(
      Hb, hw, out_lg, N, 20, 256, 256, 256, 20, hb, pm);
  // 7. final LN
  outx_k<<<N, 256, 0, stream>>>(x, AG, inv, ens, enb, out_x);
}

// Round 2
// 347.067 us; speedup vs baseline: 1.1528x; 1.1528x over previous
//
#include <hip/hip_runtime.h>
#include <math.h>

// Round 7: fuse the entire residual MLP (3x LN+GEMM+GEMM+resid) + head into a
// single kernel (mlp_fused). h stays resident in LDS; weights stream directly
// global->VGPR (L2-hot, no LDS staging, no k-loop barriers). Removes 10
// dispatches and all intermediate activation traffic. attn/unpack/LN512/ag
// identical to round 6.

typedef short bf8 __attribute__((ext_vector_type(8)));
typedef short bf4 __attribute__((ext_vector_type(4)));
typedef float f32x4 __attribute__((ext_vector_type(4)));
typedef unsigned short u16;

constexpr int LDT = 40;  // LDS row stride in shorts (32 data + 8 pad)
enum { EPI_NONE = 0, EPI_BIAS_RELU = 1, EPI_BIAS = 2, EPI_RESID = 3 };
#define RSQRT2 0.70710678118654752f

__device__ __forceinline__ u16 f2bf(float f) {
  unsigned int u = __builtin_bit_cast(unsigned int, f);
  unsigned int r = u + 0x7fffu + ((u >> 16) & 1u);  // RNE
  return (u16)(r >> 16);
}
__device__ __forceinline__ float bf2f(u16 v) {
  return __builtin_bit_cast(float, (unsigned int)v << 16);
}
__device__ __forceinline__ f32x4 mfma16(bf8 a, bf8 b, f32x4 c) {
  return __builtin_amdgcn_mfma_f32_16x16x32_bf16(a, b, c, 0, 0, 0);
}

// ---------------- batched f32 -> bf16 conversion -----------------------------
struct CvtDesc { const float* src; u16* dst; int n; };
struct CvtArgs { CvtDesc d[8]; };

__global__ __launch_bounds__(256) void cvt_k(CvtArgs a) {
  CvtDesc d = a.d[blockIdx.z];
  int i = (blockIdx.x * 256 + threadIdx.x) * 8;
  if (i >= d.n) return;
  f32x4 v0 = *(const f32x4*)(d.src + i);
  f32x4 v1 = *(const f32x4*)(d.src + i + 4);
  bf8 o;
  o[0] = (short)f2bf(v0[0]); o[1] = (short)f2bf(v0[1]);
  o[2] = (short)f2bf(v0[2]); o[3] = (short)f2bf(v0[3]);
  o[4] = (short)f2bf(v1[0]); o[5] = (short)f2bf(v1[1]);
  o[6] = (short)f2bf(v1[2]); o[7] = (short)f2bf(v1[3]);
  *(bf8*)(d.dst + i) = o;
}

// ------- 128x64-tile bf16 GEMM: C[M,N] = A[M,K](bf16) @ B[N,K](bf16)^T ------
template <int EPI, bool BFOUT>
__global__ __launch_bounds__(256) void mgemm2(
    const u16* __restrict__ A, const u16* __restrict__ B,
    void* __restrict__ Cv, int M, int N, int K, int lda, int ldb, int ldc,
    const float* __restrict__ bias, const float* __restrict__ Hin,
    const int* __restrict__ gatherA, const int* __restrict__ scatterC) {
  __shared__ __align__(16) u16 As[128 * LDT];
  __shared__ __align__(16) u16 Bs[64 * LDT];
  const int tid = threadIdx.x;
  const int m0 = blockIdx.y * 128, n0 = blockIdx.x * 64;
  const int wave = tid >> 6, lane = tid & 63;
  const int wm = (wave & 1) * 64, wn = (wave >> 1) * 32;
  const int lrow = lane & 15, quad = lane >> 4;
  const int srow = tid >> 2, skq = tid & 3;

  int gr0 = m0 + srow, gr1 = m0 + srow + 64;
  int ar0 = (gr0 < M) ? (gatherA ? gatherA[gr0] : gr0) : -1;
  int ar1 = (gr1 < M) ? (gatherA ? gatherA[gr1] : gr1) : -1;
  const u16* Ap0 = (ar0 >= 0) ? A + (size_t)ar0 * lda + skq * 8 : nullptr;
  const u16* Ap1 = (ar1 >= 0) ? A + (size_t)ar1 * lda + skq * 8 : nullptr;
  const u16* Bp = (n0 + srow < N) ? B + (size_t)(n0 + srow) * ldb + skq * 8 : nullptr;
  u16* AsW0 = &As[srow * LDT + skq * 8];
  u16* AsW1 = &As[(srow + 64) * LDT + skq * 8];
  u16* BsW = &Bs[srow * LDT + skq * 8];

  f32x4 acc[4][2];
#pragma unroll
  for (int i = 0; i < 4; ++i)
#pragma unroll
    for (int j = 0; j < 2; ++j) acc[i][j] = (f32x4){0.f, 0.f, 0.f, 0.f};
  const bf8 z8 = {0, 0, 0, 0, 0, 0, 0, 0};

  for (int k0 = 0; k0 < K; k0 += 32) {
    bf8 a0 = Ap0 ? *(const bf8*)(Ap0 + k0) : z8;
    bf8 a1 = Ap1 ? *(const bf8*)(Ap1 + k0) : z8;
    bf8 bv = Bp ? *(const bf8*)(Bp + k0) : z8;
    *(bf8*)AsW0 = a0;
    *(bf8*)AsW1 = a1;
    *(bf8*)BsW = bv;
    __syncthreads();
    bf8 af[4], bfr[2];
#pragma unroll
    for (int i = 0; i < 4; ++i)
      af[i] = *(const bf8*)&As[(wm + i * 16 + lrow) * LDT + quad * 8];
#pragma unroll
    for (int j = 0; j < 2; ++j)
      bfr[j] = *(const bf8*)&Bs[(wn + j * 16 + lrow) * LDT + quad * 8];
#pragma unroll
    for (int i = 0; i < 4; ++i)
#pragma unroll
      for (int j = 0; j < 2; ++j) acc[i][j] = mfma16(af[i], bfr[j], acc[i][j]);
    __syncthreads();
  }

  float* Cf = (float*)Cv;
  u16* Cb = (u16*)Cv;
#pragma unroll
  for (int i = 0; i < 4; ++i) {
#pragma unroll
    for (int r = 0; r < 4; ++r) {
      int row = m0 + wm + i * 16 + quad * 4 + r;
      if (row >= M) continue;
      if (gatherA && gatherA[row] < 0) continue;
      int orow = scatterC ? scatterC[row] : row;
#pragma unroll
      for (int j = 0; j < 2; ++j) {
        int col = n0 + wn + j * 16 + lrow;
        if (col >= N) continue;
        float v = acc[i][j][r];
        if (EPI == EPI_BIAS_RELU) v = fmaxf(v + bias[col], 0.f);
        else if (EPI == EPI_BIAS) v += bias[col];
        else if (EPI == EPI_RESID) v = (Hin[(size_t)row * ldc + col] + v + bias[col]) * RSQRT2;
        if (BFOUT) Cb[(size_t)orow * ldc + col] = f2bf(v);
        else Cf[(size_t)orow * ldc + col] = v;
      }
    }
  }
}

// ---------------- V transpose: KV[b][s][512+hd] -> VT[b][hd][s] (bf16) -------
__global__ __launch_bounds__(256) void vtrans(const u16* __restrict__ KV,
                                              u16* __restrict__ VT) {
  __shared__ u16 t[32][33];
  int b = blockIdx.z;
  int s0 = blockIdx.x * 32, d0 = blockIdx.y * 32;
  int tx = threadIdx.x & 31, ty = threadIdx.x >> 5;
#pragma unroll
  for (int i = 0; i < 32; i += 8)
    t[ty + i][tx] = KV[(size_t)(b * 512 + s0 + ty + i) * 1024 + 512 + d0 + tx];
  __syncthreads();
#pragma unroll
  for (int i = 0; i < 32; i += 8)
    VT[(size_t)(b * 512 + d0 + ty + i) * 512 + s0 + tx] = t[tx][ty + i];
}

// ---------------- fused attention: per (b,h,mtile32) -------------------------
constexpr int WST = 520;  // W row stride (512 + 8 pad) -> 65 granules (odd)
constexpr int QST = 72;   // Q/K/V row stride (64 + 8 pad) -> 9 granules (odd)

__global__ __launch_bounds__(256) void attn_fused(
    const u16* __restrict__ Q, const u16* __restrict__ KV,
    const u16* __restrict__ VT, const int* __restrict__ list,
    const float* __restrict__ mask, u16* __restrict__ packed,
    u16* __restrict__ feat, int N) {
  const int b = blockIdx.y >> 3, h = blockIdx.y & 7;
  const int mt = blockIdx.x;
  const int* lst = list + (size_t)b * N + mt * 32;
  if (lst[0] < 0) return;

  __shared__ __align__(16) u16 Ws[32 * WST];
  __shared__ __align__(16) u16 Qs[32 * QST];
  __shared__ __align__(16) u16 KVs[64 * QST];  // K tiles (A) / V chunks (B)
  __shared__ __align__(16) float mk[8][68];    // mask, padded
  __shared__ int mS[32];

  const int tid = threadIdx.x;
  const int wave = tid >> 6, lane = tid & 63;
  const int wm = (wave & 1) * 16, wns = (wave >> 1) * 32;
  const int lrow = lane & 15, quad = lane >> 4;
  const bf8 z8 = {0, 0, 0, 0, 0, 0, 0, 0};

  if (tid < 32) mS[tid] = lst[tid];
  {  // stage mask into padded layout (float2 per thread)
    int p = tid >> 5, j = (tid & 31) * 2;
    *(float2*)&mk[p][j] = *(const float2*)&mask[(size_t)b * 512 + p * 64 + j];
  }
  {  // stage Q tile: 32 rows x 64k
    int qr = tid >> 3, kq = tid & 7;
    int m = lst[qr];
    *(bf8*)&Qs[qr * QST + kq * 8] =
        (m >= 0) ? *(const bf8*)(Q + (size_t)m * 512 + h * 64 + kq * 8) : z8;
  }
  __syncthreads();

  const bf8 qa0 = *(const bf8*)&Qs[(wm + lrow) * QST + 0 + quad * 8];
  const bf8 qa1 = *(const bf8*)&Qs[(wm + lrow) * QST + 32 + quad * 8];

  // ---- Phase A: scores ----
  const u16* KVb = KV + (size_t)(b * 512) * 1024 + h * 64;
  for (int st = 0; st < 8; ++st) {
#pragma unroll
    for (int i = 0; i < 2; ++i) {  // stage K tile: 64 rows x 64k
      int c = tid * 2 + i;
      int sr = c >> 3, kq = c & 7;
      *(bf8*)&KVs[sr * QST + kq * 8] =
          *(const bf8*)(KVb + (size_t)(st * 64 + sr) * 1024 + kq * 8);
    }
    __syncthreads();
    f32x4 acc0 = {0.f, 0.f, 0.f, 0.f}, acc1 = acc0;
    {
      bf8 b00 = *(const bf8*)&KVs[(wns + lrow) * QST + quad * 8];
      bf8 b10 = *(const bf8*)&KVs[(wns + 16 + lrow) * QST + quad * 8];
      bf8 b01 = *(const bf8*)&KVs[(wns + lrow) * QST + 32 + quad * 8];
      bf8 b11 = *(const bf8*)&KVs[(wns + 16 + lrow) * QST + 32 + quad * 8];
      acc0 = mfma16(qa0, b00, acc0);
      acc1 = mfma16(qa0, b10, acc1);
      acc0 = mfma16(qa1, b01, acc0);
      acc1 = mfma16(qa1, b11, acc1);
    }
#pragma unroll
    for (int r = 0; r < 4; ++r) {
      int lr = wm + quad * 4 + r;
      Ws[lr * WST + st * 64 + wns + lrow] = f2bf(acc0[r] * 0.125f);
      Ws[lr * WST + st * 64 + wns + 16 + lrow] = f2bf(acc1[r] * 0.125f);
    }
    __syncthreads();
  }

  // ---- Stats + W rebuild: 8 lanes per row, vectorized, shfl reductions ----
  {
    const int row = tid >> 3, part = tid & 7;
    u16* wrow = &Ws[row * WST + part * 64];
    const int mm = mS[row];
    bf8 w[8];
    float mx = -1e30f;
#pragma unroll
    for (int v = 0; v < 8; ++v) {
      w[v] = *(const bf8*)(wrow + v * 8);
#pragma unroll
      for (int j = 0; j < 8; ++j) mx = fmaxf(mx, bf2f((u16)w[v][j]));
    }
    if (mm >= 0) {  // packed raw scores, 16B coalesced stores
      u16* prow = packed + ((size_t)h * N + mm) * 512 + part * 64;
#pragma unroll
      for (int v = 0; v < 8; ++v) *(bf8*)(prow + v * 8) = w[v];
    }
#pragma unroll
    for (int d = 1; d < 8; d <<= 1) mx = fmaxf(mx, __shfl_xor(mx, d));
    float se = 0.f, ms = 0.f;
#pragma unroll
    for (int v = 0; v < 8; ++v) {
      f32x4 m0 = *(const f32x4*)&mk[part][v * 8];
      f32x4 m1 = *(const f32x4*)&mk[part][v * 8 + 4];
#pragma unroll
      for (int j = 0; j < 8; ++j) {
        float e = __expf(bf2f((u16)w[v][j]) - mx);
        se += e;
        ms += e * (j < 4 ? m0[j] : m1[j - 4]);
      }
    }
#pragma unroll
    for (int d = 1; d < 8; d <<= 1) {
      se += __shfl_xor(se, d);
      ms += __shfl_xor(ms, d);
    }
    float iv = 1.0f / (ms + 1e-6f * se);
#pragma unroll
    for (int v = 0; v < 8; ++v) {
      f32x4 m0 = *(const f32x4*)&mk[part][v * 8];
      f32x4 m1 = *(const f32x4*)&mk[part][v * 8 + 4];
      bf8 o;
#pragma unroll
      for (int j = 0; j < 8; ++j) {
        float e = __expf(bf2f((u16)w[v][j]) - mx);
        o[j] = (short)f2bf(e * (j < 4 ? m0[j] : m1[j - 4]) * iv);
      }
      *(bf8*)(wrow + v * 8) = o;
    }
  }
  __syncthreads();

  // ---- Phase B: feat = W @ VT^T  (32m x 64d, K=512), 64-wide s chunks ----
  f32x4 acc0 = {0.f, 0.f, 0.f, 0.f}, acc1 = acc0;
  const u16* VTb = VT + (size_t)(b * 512 + h * 64) * 512;
  for (int s0 = 0; s0 < 512; s0 += 64) {
#pragma unroll
    for (int i = 0; i < 2; ++i) {  // stage V chunk: 64 d-rows x 64 s
      int c = tid * 2 + i;
      int sr = c >> 3, kq = c & 7;
      *(bf8*)&KVs[sr * QST + kq * 8] =
          *(const bf8*)(VTb + (size_t)sr * 512 + s0 + kq * 8);
    }
    __syncthreads();
#pragma unroll
    for (int k0 = 0; k0 < 64; k0 += 32) {
      bf8 a = *(const bf8*)&Ws[(wm + lrow) * WST + s0 + k0 + quad * 8];
      bf8 b0 = *(const bf8*)&KVs[(wns + lrow) * QST + k0 + quad * 8];
      bf8 b1 = *(const bf8*)&KVs[(wns + 16 + lrow) * QST + k0 + quad * 8];
      acc0 = mfma16(a, b0, acc0);
      acc1 = mfma16(a, b1, acc1);
    }
    __syncthreads();
  }
#pragma unroll
  for (int r = 0; r < 4; ++r) {
    int lr = wm + quad * 4 + r;
    int mm = mS[lr];
    if (mm < 0) continue;
    u16* frow = feat + (size_t)mm * 512 + h * 64;
    frow[wns + lrow] = f2bf(acc0[r]);
    frow[wns + 16 + lrow] = f2bf(acc1[r]);
  }
}

// ---------------- unpack: packed[h][m][s] -> out_sc[pm[m]][s][h] fp32 --------
__global__ __launch_bounds__(256) void unpack_k(const u16* __restrict__ packed,
                                                const int* __restrict__ pm,
                                                float* __restrict__ out_sc,
                                                int N) {
  __shared__ u16 Ls[8 * 520];
  int m = blockIdx.x, tid = threadIdx.x;
  int h = tid >> 5, c = (tid & 31) * 16;
  const u16* row = packed + ((size_t)h * N + m) * 512 + c;
  *(bf8*)&Ls[h * 520 + c] = *(const bf8*)row;
  *(bf8*)&Ls[h * 520 + c + 8] = *(const bf8*)(row + 8);
  __syncthreads();
  float* orow = out_sc + (size_t)pm[m] * 4096;
#pragma unroll
  for (int i = 0; i < 16; ++i) {
    int e = tid + i * 256;
    orow[e] = bf2f(Ls[(e & 7) * 520 + (e >> 3)]);
  }
}

// ---------------- LayerNorm over W, eps=1e-5 ---------------------------------
template <int W, bool BFIN, bool BFOUT>
__global__ __launch_bounds__(256) void ln_k(const void* __restrict__ in,
                                            void* __restrict__ out,
                                            const float* __restrict__ g,
                                            const float* __restrict__ bb) {
  constexpr int PT = W / 256;
  __shared__ float red[256];
  int row = blockIdx.x, tid = threadIdx.x;
  float v[PT];
  float s = 0.f, sq = 0.f;
#pragma unroll
  for (int p = 0; p < PT; ++p) {
    int c = tid + p * 256;
    v[p] = BFIN ? bf2f(((const u16*)in)[(size_t)row * W + c])
                : ((const float*)in)[(size_t)row * W + c];
    s += v[p];
    sq += v[p] * v[p];
  }
  red[tid] = s;
  __syncthreads();
  for (int off = 128; off; off >>= 1) {
    if (tid < off) red[tid] += red[tid + off];
    __syncthreads();
  }
  float mean = red[0] * (1.0f / W);
  __syncthreads();
  red[tid] = sq;
  __syncthreads();
  for (int off = 128; off; off >>= 1) {
    if (tid < off) red[tid] += red[tid + off];
    __syncthreads();
  }
  float var = red[0] * (1.0f / W) - mean * mean;
  float is = 1.0f / sqrtf(var + 1e-5f);
#pragma unroll
  for (int p = 0; p < PT; ++p) {
    int c = tid + p * 256;
    float o = (v[p] - mean) * is * g[c] + bb[c];
    if (BFOUT) ((u16*)out)[(size_t)row * W + c] = f2bf(o);
    else ((float*)out)[(size_t)row * W + c] = o;
  }
}

// ---------------- fused residual MLP (3 layers) + head -----------------------
// One block = 32 rows. h resident in LDS (fp32) for the whole chain.
// Per layer: LN (8 lanes/row, shfl) -> As(bf16); y1 = relu(As@W1^T+b1) -> As;
// h = (h + As@W2^T + b2) * rsqrt2. Weights stream global->VGPR (L2-hot),
// so GEMM k-loops have NO barriers. Head = fp32 VALU dots, scatter via pm.
constexpr int HST = 268;  // Hs row stride in floats (256 + 12)
constexpr int AST = 280;  // As row stride in shorts (256 + 24) -> 35 granules

__global__ __launch_bounds__(256) void mlp_fused(
    const float* __restrict__ AG, const float* __restrict__ rls,
    const float* __restrict__ rlb, const u16* __restrict__ rw1,
    const float* __restrict__ rb1, const u16* __restrict__ rw2,
    const float* __restrict__ rb2, const float* __restrict__ hw,
    const float* __restrict__ hb, const int* __restrict__ pm,
    float* __restrict__ out_lg) {
  __shared__ __align__(16) float Hs[32 * HST];
  __shared__ __align__(16) u16 As[32 * AST];
  const int tid = threadIdx.x;
  const int m0 = blockIdx.x * 32;
  const int wave = tid >> 6, lane = tid & 63;
  const int lrow = lane & 15, quad = lane >> 4;
  const int wn = wave * 64;               // this wave's 64 output cols
  const int row = tid >> 3, part = tid & 7;  // LN/head mapping

  // load h = AG rows (interleaved col chunks: conflict-free, coalesced)
#pragma unroll
  for (int v = 0; v < 8; ++v) {
    int c = v * 32 + part * 4;
    *(f32x4*)&Hs[row * HST + c] = *(const f32x4*)&AG[(size_t)(m0 + row) * 256 + c];
  }

  for (int layer = 0; layer < 3; ++layer) {
    __syncthreads();  // h ready (initial load / previous epilogue)
    // ---- LN(h) -> As (bf16) ----
    {
      float s = 0.f, sq = 0.f;
      f32x4 hv[8];
#pragma unroll
      for (int v = 0; v < 8; ++v) {
        hv[v] = *(const f32x4*)&Hs[row * HST + v * 32 + part * 4];
#pragma unroll
        for (int e = 0; e < 4; ++e) { s += hv[v][e]; sq += hv[v][e] * hv[v][e]; }
      }
#pragma unroll
      for (int d = 1; d < 8; d <<= 1) { s += __shfl_xor(s, d); sq += __shfl_xor(sq, d); }
      float mean = s * (1.0f / 256.0f);
      float var = sq * (1.0f / 256.0f) - mean * mean;
      float is = 1.0f / sqrtf(var + 1e-5f);
      const float* g = rls + layer * 256;
      const float* bb = rlb + layer * 256;
#pragma unroll
      for (int v = 0; v < 8; ++v) {
        int c = v * 32 + part * 4;
        f32x4 gv = *(const f32x4*)&g[c];
        f32x4 bv = *(const f32x4*)&bb[c];
        bf4 o;
#pragma unroll
        for (int e = 0; e < 4; ++e)
          o[e] = (short)f2bf((hv[v][e] - mean) * is * gv[e] + bv[e]);
        *(bf4*)&As[row * AST + c] = o;
      }
    }
    __syncthreads();  // As ready for all waves

    // ---- GEMM1: y1 = relu(As @ W1^T + b1) -> As ----
    {
      const u16* W = rw1 + (size_t)layer * 65536;
      f32x4 acc[2][4];
#pragma unroll
      for (int i = 0; i < 2; ++i)
#pragma unroll
        for (int j = 0; j < 4; ++j) acc[i][j] = (f32x4){0.f, 0.f, 0.f, 0.f};
#pragma unroll 4
      for (int k0 = 0; k0 < 256; k0 += 32) {
        bf8 a0 = *(const bf8*)&As[lrow * AST + k0 + quad * 8];
        bf8 a1 = *(const bf8*)&As[(16 + lrow) * AST + k0 + quad * 8];
#pragma unroll
        for (int nt = 0; nt < 4; ++nt) {
          bf8 bfr = *(const bf8*)&W[(size_t)(wn + nt * 16 + lrow) * 256 + k0 + quad * 8];
          acc[0][nt] = mfma16(a0, bfr, acc[0][nt]);
          acc[1][nt] = mfma16(a1, bfr, acc[1][nt]);
        }
      }
      __syncthreads();  // all As reads done before overwrite
      const float* b1 = rb1 + layer * 256;
#pragma unroll
      for (int mt = 0; mt < 2; ++mt)
#pragma unroll
        for (int nt = 0; nt < 4; ++nt) {
          int col = wn + nt * 16 + lrow;
          float bias = b1[col];
#pragma unroll
          for (int r = 0; r < 4; ++r) {
            int rr = mt * 16 + quad * 4 + r;
            As[rr * AST + col] = f2bf(fmaxf(acc[mt][nt][r] + bias, 0.f));
          }
        }
    }
    __syncthreads();  // y1 in As ready for all waves

    // ---- GEMM2: h = (h + As @ W2^T + b2) * rsqrt2 ----
    {
      const u16* W = rw2 + (size_t)layer * 65536;
      f32x4 acc[2][4];
#pragma unroll
      for (int i = 0; i < 2; ++i)
#pragma unroll
        for (int j = 0; j < 4; ++j) acc[i][j] = (f32x4){0.f, 0.f, 0.f, 0.f};
#pragma unroll 4
      for (int k0 = 0; k0 < 256; k0 += 32) {
        bf8 a0 = *(const bf8*)&As[lrow * AST + k0 + quad * 8];
        bf8 a1 = *(const bf8*)&As[(16 + lrow) * AST + k0 + quad * 8];
#pragma unroll
        for (int nt = 0; nt < 4; ++nt) {
          bf8 bfr = *(const bf8*)&W[(size_t)(wn + nt * 16 + lrow) * 256 + k0 + quad * 8];
          acc[0][nt] = mfma16(a0, bfr, acc[0][nt]);
          acc[1][nt] = mfma16(a1, bfr, acc[1][nt]);
        }
      }
      const float* b2 = rb2 + layer * 256;
#pragma unroll
      for (int mt = 0; mt < 2; ++mt)
#pragma unroll
        for (int nt = 0; nt < 4; ++nt) {
          int col = wn + nt * 16 + lrow;
          float bias = b2[col];
#pragma unroll
          for (int r = 0; r < 4; ++r) {
            int rr = mt * 16 + quad * 4 + r;
            Hs[rr * HST + col] = (Hs[rr * HST + col] + acc[mt][nt][r] + bias) * RSQRT2;
          }
        }
    }
  }
  __syncthreads();  // final h ready

  // ---- head: logits[row][c] for c = part, part+8, (part+16 if <20) ----
  {
    int orow = pm[m0 + row];
    const float* hrow = &Hs[row * HST];
    int c2 = part + 16;
    const float* w0 = hw + (size_t)part * 256;
    const float* w1 = hw + (size_t)(part + 8) * 256;
    const float* w2 = hw + (size_t)(part < 4 ? c2 : 0) * 256;
    float l0 = 0.f, l1 = 0.f, l2 = 0.f;
    for (int k = 0; k < 256; k += 4) {
      f32x4 h4 = *(const f32x4*)&hrow[k];
      f32x4 a4 = *(const f32x4*)&w0[k];
      f32x4 b4 = *(const f32x4*)&w1[k];
      f32x4 c4 = *(const f32x4*)&w2[k];
#pragma unroll
      for (int e = 0; e < 4; ++e) {
        l0 += h4[e] * a4[e];
        l1 += h4[e] * b4[e];
        l2 += h4[e] * c4[e];
      }
    }
    out_lg[(size_t)orow * 20 + part] = l0 + hb[part];
    out_lg[(size_t)orow * 20 + part + 8] = l1 + hb[part + 8];
    if (part < 4) out_lg[(size_t)orow * 20 + c2] = l2 + hb[c2];
  }
}

// ---------------- final: out_x = LN(x + scatter(ag)/sqrt2) -------------------
__global__ __launch_bounds__(256) void outx_k(
    const float* __restrict__ x, const float* __restrict__ ag,
    const int* __restrict__ inv, const float* __restrict__ g,
    const float* __restrict__ bb, float* __restrict__ out) {
  __shared__ float red[256];
  int n = blockIdx.x, tid = threadIdx.x;
  int mi = inv[n];
  float v = x[(size_t)n * 256 + tid];
  if (mi >= 0) v += ag[(size_t)mi * 256 + tid] * RSQRT2;
  red[tid] = v;
  __syncthreads();
  for (int off = 128; off; off >>= 1) {
    if (tid < off) red[tid] += red[tid + off];
    __syncthreads();
  }
  float mean = red[0] * (1.0f / 256.0f);
  __syncthreads();
  red[tid] = v * v;
  __syncthreads();
  for (int off = 128; off; off >>= 1) {
    if (tid < off) red[tid] += red[tid + off];
    __syncthreads();
  }
  float var = red[0] * (1.0f / 256.0f) - mean * mean;
  float is = 1.0f / sqrtf(var + 1e-5f);
  out[(size_t)n * 256 + tid] = (v - mean) * is * g[tid] + bb[tid];
}

// ---------------- index compaction -------------------------------------------
__global__ void init_idx_k(int* __restrict__ list, int* __restrict__ inv,
                           int* __restrict__ cnt, int N, int B) {
  int i = blockIdx.x * 256 + threadIdx.x;
  if (i < B * N) list[i] = -1;
  if (i < N) inv[i] = -1;
  if (i < B) cnt[i] = 0;
}

__global__ void compact_k(const int* __restrict__ pm,
                          const int* __restrict__ batch, int* __restrict__ list,
                          int* __restrict__ inv, int* __restrict__ cnt, int N) {
  int m = blockIdx.x * 256 + threadIdx.x;
  if (m >= N) return;
  int p = pm[m];
  int b = batch[p];
  int slot = atomicAdd(&cnt[b], 1);
  list[(size_t)b * N + slot] = m;
  inv[p] = m;
}

// -----------------------------------------------------------------------------
extern "C" void kernel_launch(void* const* d_in, const int* in_sizes, int n_in,
                              void* d_out, int out_size, void* d_ws,
                              size_t ws_size, hipStream_t stream) {
  const float* x = (const float*)d_in[0];
  const float* emb = (const float*)d_in[1];
  const float* mask = (const float*)d_in[2];
  const int* pm = (const int*)d_in[3];
  const int* batch = (const int*)d_in[4];
  const float* Wq = (const float*)d_in[5];
  const float* Wk = (const float*)d_in[6];
  const float* Wv = (const float*)d_in[7];
  const float* ag_s = (const float*)d_in[8];
  const float* ag_b = (const float*)d_in[9];
  const float* Wag = (const float*)d_in[10];
  const float* rls = (const float*)d_in[11];
  const float* rlb = (const float*)d_in[12];
  const float* rw1 = (const float*)d_in[13];
  const float* rb1 = (const float*)d_in[14];
  const float* rw2 = (const float*)d_in[15];
  const float* rb2 = (const float*)d_in[16];
  const float* hw = (const float*)d_in[17];
  const float* hb = (const float*)d_in[18];
  const float* ens = (const float*)d_in[19];
  const float* enb = (const float*)d_in[20];

  const int N = in_sizes[0] / 256;  // 4096
  const int B = in_sizes[2] / 512;  // 4

  char* wsb = (char*)d_ws;
  // conversion-phase (dead before packed is written):
  u16* embbf = (u16*)(wsb + 0);
  u16* xbf   = (u16*)(wsb + 5242880);
  u16* Wkvbf = (u16*)(wsb + 7340032);
  u16* Wqbf  = (u16*)(wsb + 9961472);
  // attention phase:
  u16* packed = (u16*)(wsb + 0);           // 32 MB
  u16* KVbf   = (u16*)(wsb + 33554432);    // 4 MB
  u16* Qbf    = (u16*)(wsb + 37748736);    // 4 MB
  u16* VT     = (u16*)(wsb + 41943040);    // 2 MB
  u16* featE  = (u16*)(wsb + 44040192);    // 4 MB
  // post-attention (aliases onto dead buffers):
  u16* LNF = (u16*)(wsb + 33554432);       // over KVbf
  float* AG = (float*)(wsb + 37748736);    // over Qbf
  // persistent:
  u16* Wagbf = (u16*)(wsb + 48234496);
  u16* rw1bf = (u16*)(wsb + 48496640);
  u16* rw2bf = (u16*)(wsb + 48889856);
  int* list  = (int*)(wsb + 49545216);
  int* inv   = (int*)(wsb + 49610752);
  int* cnt   = (int*)(wsb + 49627136);

  float* out_x = (float*)d_out;
  float* out_lg = out_x + (size_t)N * 256;
  float* out_sc = out_lg + (size_t)N * 20;

  // 0. conversions + index compaction
  CvtArgs ca;
  ca.d[0] = {emb, embbf, 2 * 512 * 1280 * 2};
  ca.d[1] = {x, xbf, 4096 * 256};
  ca.d[2] = {Wk, Wkvbf, 512 * 1280};
  ca.d[3] = {Wv, Wkvbf + 512 * 1280, 512 * 1280};
  ca.d[4] = {Wq, Wqbf, 512 * 256};
  ca.d[5] = {Wag, Wagbf, 256 * 512};
  ca.d[6] = {rw1, rw1bf, 3 * 256 * 256};
  ca.d[7] = {rw2, rw2bf, 3 * 256 * 256};
  cvt_k<<<dim3(1281, 1, 8), 256, 0, stream>>>(ca);
  init_idx_k<<<(B * N + 255) / 256, 256, 0, stream>>>(list, inv, cnt, N, B);
  compact_k<<<(N + 255) / 256, 256, 0, stream>>>(pm, batch, list, inv, cnt, N);

  // 1. fused K+V projection
  mgemm2<EPI_NONE, true><<<dim3(16, 16), 256, 0, stream>>>(
      embbf, Wkvbf, KVbf, B * 512, 1024, 1280, 1280, 1280, 1024,
      nullptr, nullptr, nullptr, nullptr);
  // 2. Q projection with gather
  mgemm2<EPI_NONE, true><<<dim3(8, 32), 256, 0, stream>>>(
      xbf, Wqbf, Qbf, N, 512, 256, 256, 256, 512,
      nullptr, nullptr, pm, nullptr);
  vtrans<<<dim3(16, 16, B), 256, 0, stream>>>(KVbf, VT);

  // 3. fused attention (scores+softmax+PV), then unpack for the fp32 output
  attn_fused<<<dim3(N / 32, B * 8), 256, 0, stream>>>(
      Qbf, KVbf, VT, list, mask, packed, featE, N);
  unpack_k<<<N, 256, 0, stream>>>(packed, pm, out_sc, N);

  // 4. ag = LN(feat) @ Wag^T
  ln_k<512, true, true><<<N, 256, 0, stream>>>(featE, LNF, ag_s, ag_b);
  mgemm2<EPI_NONE, false><<<dim3(4, 32), 256, 0, stream>>>(
      LNF, Wagbf, AG, N, 256, 512, 512, 512, 256,
      nullptr, nullptr, nullptr, nullptr);

  // 5+6. fused residual MLP + head (replaces 10 dispatches)
  mlp_fused<<<dim3(N / 32), 256, 0, stream>>>(
      AG, rls, rlb, rw1bf, rb1, rw2bf, rb2, hw, hb, pm, out_lg);

  // 7. final LN
  outx_k<<<N, 256, 0, stream>>>(x, AG, inv, ens, enb, out_x);
}

// Round 3
// 310.488 us; speedup vs baseline: 1.2886x; 1.1178x over previous
//
#include <hip/hip_runtime.h>
#include <math.h>

// Round 8: mlp_fused v2 — occupancy + deeper fusion.
//  - 16 rows/block x 256 blocks (full CU coverage), 512 threads (8 waves/CU)
//  - folds LN512(feat) + AG GEMM (K=512, Wag) into the same kernel: feat ->
//    LN -> ag (written to global for outx) -> h in LDS -> 3 residual layers
//    -> head logits. ln_k + AG mgemm2 dispatches removed.
//  - ping-pong activation buffers: 3 barriers/layer, no As overwrite hazard.
// attn/unpack/projections identical to round 7.

typedef short bf8 __attribute__((ext_vector_type(8)));
typedef float f32x4 __attribute__((ext_vector_type(4)));
typedef unsigned short u16;

constexpr int LDT = 40;  // LDS row stride in shorts (32 data + 8 pad)
enum { EPI_NONE = 0, EPI_BIAS_RELU = 1, EPI_BIAS = 2, EPI_RESID = 3 };
#define RSQRT2 0.70710678118654752f

__device__ __forceinline__ u16 f2bf(float f) {
  unsigned int u = __builtin_bit_cast(unsigned int, f);
  unsigned int r = u + 0x7fffu + ((u >> 16) & 1u);  // RNE
  return (u16)(r >> 16);
}
__device__ __forceinline__ float bf2f(u16 v) {
  return __builtin_bit_cast(float, (unsigned int)v << 16);
}
__device__ __forceinline__ f32x4 mfma16(bf8 a, bf8 b, f32x4 c) {
  return __builtin_amdgcn_mfma_f32_16x16x32_bf16(a, b, c, 0, 0, 0);
}

// ---------------- batched f32 -> bf16 conversion -----------------------------
struct CvtDesc { const float* src; u16* dst; int n; };
struct CvtArgs { CvtDesc d[8]; };

__global__ __launch_bounds__(256) void cvt_k(CvtArgs a) {
  CvtDesc d = a.d[blockIdx.z];
  int i = (blockIdx.x * 256 + threadIdx.x) * 8;
  if (i >= d.n) return;
  f32x4 v0 = *(const f32x4*)(d.src + i);
  f32x4 v1 = *(const f32x4*)(d.src + i + 4);
  bf8 o;
  o[0] = (short)f2bf(v0[0]); o[1] = (short)f2bf(v0[1]);
  o[2] = (short)f2bf(v0[2]); o[3] = (short)f2bf(v0[3]);
  o[4] = (short)f2bf(v1[0]); o[5] = (short)f2bf(v1[1]);
  o[6] = (short)f2bf(v1[2]); o[7] = (short)f2bf(v1[3]);
  *(bf8*)(d.dst + i) = o;
}

// ------- 128x64-tile bf16 GEMM: C[M,N] = A[M,K](bf16) @ B[N,K](bf16)^T ------
template <int EPI, bool BFOUT>
__global__ __launch_bounds__(256) void mgemm2(
    const u16* __restrict__ A, const u16* __restrict__ B,
    void* __restrict__ Cv, int M, int N, int K, int lda, int ldb, int ldc,
    const float* __restrict__ bias, const float* __restrict__ Hin,
    const int* __restrict__ gatherA, const int* __restrict__ scatterC) {
  __shared__ __align__(16) u16 As[128 * LDT];
  __shared__ __align__(16) u16 Bs[64 * LDT];
  const int tid = threadIdx.x;
  const int m0 = blockIdx.y * 128, n0 = blockIdx.x * 64;
  const int wave = tid >> 6, lane = tid & 63;
  const int wm = (wave & 1) * 64, wn = (wave >> 1) * 32;
  const int lrow = lane & 15, quad = lane >> 4;
  const int srow = tid >> 2, skq = tid & 3;

  int gr0 = m0 + srow, gr1 = m0 + srow + 64;
  int ar0 = (gr0 < M) ? (gatherA ? gatherA[gr0] : gr0) : -1;
  int ar1 = (gr1 < M) ? (gatherA ? gatherA[gr1] : gr1) : -1;
  const u16* Ap0 = (ar0 >= 0) ? A + (size_t)ar0 * lda + skq * 8 : nullptr;
  const u16* Ap1 = (ar1 >= 0) ? A + (size_t)ar1 * lda + skq * 8 : nullptr;
  const u16* Bp = (n0 + srow < N) ? B + (size_t)(n0 + srow) * ldb + skq * 8 : nullptr;
  u16* AsW0 = &As[srow * LDT + skq * 8];
  u16* AsW1 = &As[(srow + 64) * LDT + skq * 8];
  u16* BsW = &Bs[srow * LDT + skq * 8];

  f32x4 acc[4][2];
#pragma unroll
  for (int i = 0; i < 4; ++i)
#pragma unroll
    for (int j = 0; j < 2; ++j) acc[i][j] = (f32x4){0.f, 0.f, 0.f, 0.f};
  const bf8 z8 = {0, 0, 0, 0, 0, 0, 0, 0};

  for (int k0 = 0; k0 < K; k0 += 32) {
    bf8 a0 = Ap0 ? *(const bf8*)(Ap0 + k0) : z8;
    bf8 a1 = Ap1 ? *(const bf8*)(Ap1 + k0) : z8;
    bf8 bv = Bp ? *(const bf8*)(Bp + k0) : z8;
    *(bf8*)AsW0 = a0;
    *(bf8*)AsW1 = a1;
    *(bf8*)BsW = bv;
    __syncthreads();
    bf8 af[4], bfr[2];
#pragma unroll
    for (int i = 0; i < 4; ++i)
      af[i] = *(const bf8*)&As[(wm + i * 16 + lrow) * LDT + quad * 8];
#pragma unroll
    for (int j = 0; j < 2; ++j)
      bfr[j] = *(const bf8*)&Bs[(wn + j * 16 + lrow) * LDT + quad * 8];
#pragma unroll
    for (int i = 0; i < 4; ++i)
#pragma unroll
      for (int j = 0; j < 2; ++j) acc[i][j] = mfma16(af[i], bfr[j], acc[i][j]);
    __syncthreads();
  }

  float* Cf = (float*)Cv;
  u16* Cb = (u16*)Cv;
#pragma unroll
  for (int i = 0; i < 4; ++i) {
#pragma unroll
    for (int r = 0; r < 4; ++r) {
      int row = m0 + wm + i * 16 + quad * 4 + r;
      if (row >= M) continue;
      if (gatherA && gatherA[row] < 0) continue;
      int orow = scatterC ? scatterC[row] : row;
#pragma unroll
      for (int j = 0; j < 2; ++j) {
        int col = n0 + wn + j * 16 + lrow;
        if (col >= N) continue;
        float v = acc[i][j][r];
        if (EPI == EPI_BIAS_RELU) v = fmaxf(v + bias[col], 0.f);
        else if (EPI == EPI_BIAS) v += bias[col];
        else if (EPI == EPI_RESID) v = (Hin[(size_t)row * ldc + col] + v + bias[col]) * RSQRT2;
        if (BFOUT) Cb[(size_t)orow * ldc + col] = f2bf(v);
        else Cf[(size_t)orow * ldc + col] = v;
      }
    }
  }
}

// ---------------- V transpose: KV[b][s][512+hd] -> VT[b][hd][s] (bf16) -------
__global__ __launch_bounds__(256) void vtrans(const u16* __restrict__ KV,
                                              u16* __restrict__ VT) {
  __shared__ u16 t[32][33];
  int b = blockIdx.z;
  int s0 = blockIdx.x * 32, d0 = blockIdx.y * 32;
  int tx = threadIdx.x & 31, ty = threadIdx.x >> 5;
#pragma unroll
  for (int i = 0; i < 32; i += 8)
    t[ty + i][tx] = KV[(size_t)(b * 512 + s0 + ty + i) * 1024 + 512 + d0 + tx];
  __syncthreads();
#pragma unroll
  for (int i = 0; i < 32; i += 8)
    VT[(size_t)(b * 512 + d0 + ty + i) * 512 + s0 + tx] = t[tx][ty + i];
}

// ---------------- fused attention: per (b,h,mtile32) -------------------------
constexpr int WST = 520;  // W row stride (512 + 8 pad) -> 65 granules (odd)
constexpr int QST = 72;   // Q/K/V row stride (64 + 8 pad) -> 9 granules (odd)

__global__ __launch_bounds__(256) void attn_fused(
    const u16* __restrict__ Q, const u16* __restrict__ KV,
    const u16* __restrict__ VT, const int* __restrict__ list,
    const float* __restrict__ mask, u16* __restrict__ packed,
    u16* __restrict__ feat, int N) {
  const int b = blockIdx.y >> 3, h = blockIdx.y & 7;
  const int mt = blockIdx.x;
  const int* lst = list + (size_t)b * N + mt * 32;
  if (lst[0] < 0) return;

  __shared__ __align__(16) u16 Ws[32 * WST];
  __shared__ __align__(16) u16 Qs[32 * QST];
  __shared__ __align__(16) u16 KVs[64 * QST];  // K tiles (A) / V chunks (B)
  __shared__ __align__(16) float mk[8][68];    // mask, padded
  __shared__ int mS[32];

  const int tid = threadIdx.x;
  const int wave = tid >> 6, lane = tid & 63;
  const int wm = (wave & 1) * 16, wns = (wave >> 1) * 32;
  const int lrow = lane & 15, quad = lane >> 4;
  const bf8 z8 = {0, 0, 0, 0, 0, 0, 0, 0};

  if (tid < 32) mS[tid] = lst[tid];
  {  // stage mask into padded layout (float2 per thread)
    int p = tid >> 5, j = (tid & 31) * 2;
    *(float2*)&mk[p][j] = *(const float2*)&mask[(size_t)b * 512 + p * 64 + j];
  }
  {  // stage Q tile: 32 rows x 64k
    int qr = tid >> 3, kq = tid & 7;
    int m = lst[qr];
    *(bf8*)&Qs[qr * QST + kq * 8] =
        (m >= 0) ? *(const bf8*)(Q + (size_t)m * 512 + h * 64 + kq * 8) : z8;
  }
  __syncthreads();

  const bf8 qa0 = *(const bf8*)&Qs[(wm + lrow) * QST + 0 + quad * 8];
  const bf8 qa1 = *(const bf8*)&Qs[(wm + lrow) * QST + 32 + quad * 8];

  // ---- Phase A: scores ----
  const u16* KVb = KV + (size_t)(b * 512) * 1024 + h * 64;
  for (int st = 0; st < 8; ++st) {
#pragma unroll
    for (int i = 0; i < 2; ++i) {  // stage K tile: 64 rows x 64k
      int c = tid * 2 + i;
      int sr = c >> 3, kq = c & 7;
      *(bf8*)&KVs[sr * QST + kq * 8] =
          *(const bf8*)(KVb + (size_t)(st * 64 + sr) * 1024 + kq * 8);
    }
    __syncthreads();
    f32x4 acc0 = {0.f, 0.f, 0.f, 0.f}, acc1 = acc0;
    {
      bf8 b00 = *(const bf8*)&KVs[(wns + lrow) * QST + quad * 8];
      bf8 b10 = *(const bf8*)&KVs[(wns + 16 + lrow) * QST + quad * 8];
      bf8 b01 = *(const bf8*)&KVs[(wns + lrow) * QST + 32 + quad * 8];
      bf8 b11 = *(const bf8*)&KVs[(wns + 16 + lrow) * QST + 32 + quad * 8];
      acc0 = mfma16(qa0, b00, acc0);
      acc1 = mfma16(qa0, b10, acc1);
      acc0 = mfma16(qa1, b01, acc0);
      acc1 = mfma16(qa1, b11, acc1);
    }
#pragma unroll
    for (int r = 0; r < 4; ++r) {
      int lr = wm + quad * 4 + r;
      Ws[lr * WST + st * 64 + wns + lrow] = f2bf(acc0[r] * 0.125f);
      Ws[lr * WST + st * 64 + wns + 16 + lrow] = f2bf(acc1[r] * 0.125f);
    }
    __syncthreads();
  }

  // ---- Stats + W rebuild: 8 lanes per row, vectorized, shfl reductions ----
  {
    const int row = tid >> 3, part = tid & 7;
    u16* wrow = &Ws[row * WST + part * 64];
    const int mm = mS[row];
    bf8 w[8];
    float mx = -1e30f;
#pragma unroll
    for (int v = 0; v < 8; ++v) {
      w[v] = *(const bf8*)(wrow + v * 8);
#pragma unroll
      for (int j = 0; j < 8; ++j) mx = fmaxf(mx, bf2f((u16)w[v][j]));
    }
    if (mm >= 0) {  // packed raw scores, 16B coalesced stores
      u16* prow = packed + ((size_t)h * N + mm) * 512 + part * 64;
#pragma unroll
      for (int v = 0; v < 8; ++v) *(bf8*)(prow + v * 8) = w[v];
    }
#pragma unroll
    for (int d = 1; d < 8; d <<= 1) mx = fmaxf(mx, __shfl_xor(mx, d));
    float se = 0.f, ms = 0.f;
#pragma unroll
    for (int v = 0; v < 8; ++v) {
      f32x4 m0 = *(const f32x4*)&mk[part][v * 8];
      f32x4 m1 = *(const f32x4*)&mk[part][v * 8 + 4];
#pragma unroll
      for (int j = 0; j < 8; ++j) {
        float e = __expf(bf2f((u16)w[v][j]) - mx);
        se += e;
        ms += e * (j < 4 ? m0[j] : m1[j - 4]);
      }
    }
#pragma unroll
    for (int d = 1; d < 8; d <<= 1) {
      se += __shfl_xor(se, d);
      ms += __shfl_xor(ms, d);
    }
    float iv = 1.0f / (ms + 1e-6f * se);
#pragma unroll
    for (int v = 0; v < 8; ++v) {
      f32x4 m0 = *(const f32x4*)&mk[part][v * 8];
      f32x4 m1 = *(const f32x4*)&mk[part][v * 8 + 4];
      bf8 o;
#pragma unroll
      for (int j = 0; j < 8; ++j) {
        float e = __expf(bf2f((u16)w[v][j]) - mx);
        o[j] = (short)f2bf(e * (j < 4 ? m0[j] : m1[j - 4]) * iv);
      }
      *(bf8*)(wrow + v * 8) = o;
    }
  }
  __syncthreads();

  // ---- Phase B: feat = W @ VT^T  (32m x 64d, K=512), 64-wide s chunks ----
  f32x4 acc0 = {0.f, 0.f, 0.f, 0.f}, acc1 = acc0;
  const u16* VTb = VT + (size_t)(b * 512 + h * 64) * 512;
  for (int s0 = 0; s0 < 512; s0 += 64) {
#pragma unroll
    for (int i = 0; i < 2; ++i) {  // stage V chunk: 64 d-rows x 64 s
      int c = tid * 2 + i;
      int sr = c >> 3, kq = c & 7;
      *(bf8*)&KVs[sr * QST + kq * 8] =
          *(const bf8*)(VTb + (size_t)sr * 512 + s0 + kq * 8);
    }
    __syncthreads();
#pragma unroll
    for (int k0 = 0; k0 < 64; k0 += 32) {
      bf8 a = *(const bf8*)&Ws[(wm + lrow) * WST + s0 + k0 + quad * 8];
      bf8 b0 = *(const bf8*)&KVs[(wns + lrow) * QST + k0 + quad * 8];
      bf8 b1 = *(const bf8*)&KVs[(wns + 16 + lrow) * QST + k0 + quad * 8];
      acc0 = mfma16(a, b0, acc0);
      acc1 = mfma16(a, b1, acc1);
    }
    __syncthreads();
  }
#pragma unroll
  for (int r = 0; r < 4; ++r) {
    int lr = wm + quad * 4 + r;
    int mm = mS[lr];
    if (mm < 0) continue;
    u16* frow = feat + (size_t)mm * 512 + h * 64;
    frow[wns + lrow] = f2bf(acc0[r]);
    frow[wns + 16 + lrow] = f2bf(acc1[r]);
  }
}

// ---------------- unpack: packed[h][m][s] -> out_sc[pm[m]][s][h] fp32 --------
__global__ __launch_bounds__(256) void unpack_k(const u16* __restrict__ packed,
                                                const int* __restrict__ pm,
                                                float* __restrict__ out_sc,
                                                int N) {
  __shared__ u16 Ls[8 * 520];
  int m = blockIdx.x, tid = threadIdx.x;
  int h = tid >> 5, c = (tid & 31) * 16;
  const u16* row = packed + ((size_t)h * N + m) * 512 + c;
  *(bf8*)&Ls[h * 520 + c] = *(const bf8*)row;
  *(bf8*)&Ls[h * 520 + c + 8] = *(const bf8*)(row + 8);
  __syncthreads();
  float* orow = out_sc + (size_t)pm[m] * 4096;
#pragma unroll
  for (int i = 0; i < 16; ++i) {
    int e = tid + i * 256;
    orow[e] = bf2f(Ls[(e & 7) * 520 + (e >> 3)]);
  }
}

// ------- fused: LN512(feat) -> ag(=h) -> 3x residual MLP -> head -------------
// 16 rows/block (256 blocks), 512 threads (8 waves). h resident in LDS fp32.
// Wave w owns output cols [w*32, w*32+32). Weights stream global->VGPR (L2).
// ag additionally written to global (outx_k input).
constexpr int HST = 268;   // Hs row stride in floats (67 granules, odd)
constexpr int AST = 520;   // As row stride in shorts (65 granules, odd)
constexpr int YST = 280;   // Ys row stride in shorts (35 granules, odd)

__global__ __launch_bounds__(512) void mlp_fused(
    const u16* __restrict__ feat, const float* __restrict__ ag_s,
    const float* __restrict__ ag_b, const u16* __restrict__ Wag,
    float* __restrict__ AGout, const float* __restrict__ rls,
    const float* __restrict__ rlb, const u16* __restrict__ rw1,
    const float* __restrict__ rb1, const u16* __restrict__ rw2,
    const float* __restrict__ rb2, const float* __restrict__ hw,
    const float* __restrict__ hb, const int* __restrict__ pm,
    float* __restrict__ out_lg) {
  __shared__ __align__(16) float Hs[16 * HST];
  __shared__ __align__(16) u16 As[16 * AST];   // LN outputs (512 or 256 wide)
  __shared__ __align__(16) u16 Ys[16 * YST];   // relu(GEMM1) outputs
  const int tid = threadIdx.x;
  const int m0 = blockIdx.x * 16;
  const int wave = tid >> 6, lane = tid & 63;
  const int lrow = lane & 15, quad = lane >> 4;
  const int wn = wave * 32;                  // this wave's 32 output cols
  const int row = tid >> 5, part = tid & 31; // LN/head mapping (32 lanes/row)

  // ---- LN512(feat) -> As (bf16), 16 cols per lane ----
  {
    const u16* frow = feat + (size_t)(m0 + row) * 512 + part * 16;
    bf8 f0 = *(const bf8*)frow;
    bf8 f1 = *(const bf8*)(frow + 8);
    float s = 0.f, sq = 0.f;
#pragma unroll
    for (int j = 0; j < 8; ++j) {
      float a = bf2f((u16)f0[j]), b = bf2f((u16)f1[j]);
      s += a + b;
      sq += a * a + b * b;
    }
#pragma unroll
    for (int d = 1; d < 32; d <<= 1) { s += __shfl_xor(s, d); sq += __shfl_xor(sq, d); }
    float mean = s * (1.0f / 512.0f);
    float var = sq * (1.0f / 512.0f) - mean * mean;
    float is = 1.0f / sqrtf(var + 1e-5f);
    int c = part * 16;
    bf8 o0, o1;
#pragma unroll
    for (int j = 0; j < 8; ++j) {
      o0[j] = (short)f2bf((bf2f((u16)f0[j]) - mean) * is * ag_s[c + j] + ag_b[c + j]);
      o1[j] = (short)f2bf((bf2f((u16)f1[j]) - mean) * is * ag_s[c + 8 + j] + ag_b[c + 8 + j]);
    }
    *(bf8*)&As[row * AST + c] = o0;
    *(bf8*)&As[row * AST + c + 8] = o1;
  }
  __syncthreads();

  // ---- AG GEMM: h = ag = LN(feat) @ Wag^T  (16m x 32n/wave, K=512) ----
  {
    f32x4 acc0 = {0.f, 0.f, 0.f, 0.f}, acc1 = acc0;
#pragma unroll 4
    for (int k0 = 0; k0 < 512; k0 += 32) {
      bf8 a = *(const bf8*)&As[lrow * AST + k0 + quad * 8];
      bf8 w0 = *(const bf8*)&Wag[(size_t)(wn + lrow) * 512 + k0 + quad * 8];
      bf8 w1 = *(const bf8*)&Wag[(size_t)(wn + 16 + lrow) * 512 + k0 + quad * 8];
      acc0 = mfma16(a, w0, acc0);
      acc1 = mfma16(a, w1, acc1);
    }
#pragma unroll
    for (int r = 0; r < 4; ++r) {
      int rr = quad * 4 + r;
      Hs[rr * HST + wn + lrow] = acc0[r];
      Hs[rr * HST + wn + 16 + lrow] = acc1[r];
      AGout[(size_t)(m0 + rr) * 256 + wn + lrow] = acc0[r];
      AGout[(size_t)(m0 + rr) * 256 + wn + 16 + lrow] = acc1[r];
    }
  }

  // ---- 3 residual layers ----
  for (int layer = 0; layer < 3; ++layer) {
    __syncthreads();  // Hs ready
    // LN(h) -> As (8 cols per lane)
    {
      int c = part * 8;
      f32x4 h0 = *(const f32x4*)&Hs[row * HST + c];
      f32x4 h1 = *(const f32x4*)&Hs[row * HST + c + 4];
      float s = 0.f, sq = 0.f;
#pragma unroll
      for (int e = 0; e < 4; ++e) {
        s += h0[e] + h1[e];
        sq += h0[e] * h0[e] + h1[e] * h1[e];
      }
#pragma unroll
      for (int d = 1; d < 32; d <<= 1) { s += __shfl_xor(s, d); sq += __shfl_xor(sq, d); }
      float mean = s * (1.0f / 256.0f);
      float var = sq * (1.0f / 256.0f) - mean * mean;
      float is = 1.0f / sqrtf(var + 1e-5f);
      const float* g = rls + layer * 256;
      const float* bb = rlb + layer * 256;
      bf8 o;
#pragma unroll
      for (int e = 0; e < 4; ++e) {
        o[e] = (short)f2bf((h0[e] - mean) * is * g[c + e] + bb[c + e]);
        o[e + 4] = (short)f2bf((h1[e] - mean) * is * g[c + 4 + e] + bb[c + 4 + e]);
      }
      *(bf8*)&As[row * AST + c] = o;
    }
    __syncthreads();  // As ready

    // GEMM1: Ys = relu(As @ W1^T + b1)
    {
      const u16* W = rw1 + (size_t)layer * 65536;
      f32x4 acc0 = {0.f, 0.f, 0.f, 0.f}, acc1 = acc0;
#pragma unroll 4
      for (int k0 = 0; k0 < 256; k0 += 32) {
        bf8 a = *(const bf8*)&As[lrow * AST + k0 + quad * 8];
        bf8 w0 = *(const bf8*)&W[(size_t)(wn + lrow) * 256 + k0 + quad * 8];
        bf8 w1 = *(const bf8*)&W[(size_t)(wn + 16 + lrow) * 256 + k0 + quad * 8];
        acc0 = mfma16(a, w0, acc0);
        acc1 = mfma16(a, w1, acc1);
      }
      const float* b1 = rb1 + layer * 256;
      float bi0 = b1[wn + lrow], bi1 = b1[wn + 16 + lrow];
#pragma unroll
      for (int r = 0; r < 4; ++r) {
        int rr = quad * 4 + r;
        Ys[rr * YST + wn + lrow] = f2bf(fmaxf(acc0[r] + bi0, 0.f));
        Ys[rr * YST + wn + 16 + lrow] = f2bf(fmaxf(acc1[r] + bi1, 0.f));
      }
    }
    __syncthreads();  // Ys ready

    // GEMM2: h = (h + Ys @ W2^T + b2) * rsqrt2
    {
      const u16* W = rw2 + (size_t)layer * 65536;
      f32x4 acc0 = {0.f, 0.f, 0.f, 0.f}, acc1 = acc0;
#pragma unroll 4
      for (int k0 = 0; k0 < 256; k0 += 32) {
        bf8 a = *(const bf8*)&Ys[lrow * YST + k0 + quad * 8];
        bf8 w0 = *(const bf8*)&W[(size_t)(wn + lrow) * 256 + k0 + quad * 8];
        bf8 w1 = *(const bf8*)&W[(size_t)(wn + 16 + lrow) * 256 + k0 + quad * 8];
        acc0 = mfma16(a, w0, acc0);
        acc1 = mfma16(a, w1, acc1);
      }
      const float* b2 = rb2 + layer * 256;
      float bi0 = b2[wn + lrow], bi1 = b2[wn + 16 + lrow];
#pragma unroll
      for (int r = 0; r < 4; ++r) {
        int rr = quad * 4 + r;
        float* h0 = &Hs[rr * HST + wn + lrow];
        float* h1 = &Hs[rr * HST + wn + 16 + lrow];
        *h0 = (*h0 + acc0[r] + bi0) * RSQRT2;
        *h1 = (*h1 + acc1[r] + bi1) * RSQRT2;
      }
    }
  }
  __syncthreads();  // final h ready

  // ---- head: each lane (row, part<20) computes one logit ----
  if (part < 20) {
    const float* hrow = &Hs[row * HST];
    const float* wrow = hw + (size_t)part * 256;
    float l0 = 0.f, l1 = 0.f, l2 = 0.f, l3 = 0.f;
    for (int k = 0; k < 256; k += 16) {
      f32x4 h0 = *(const f32x4*)&hrow[k];
      f32x4 h1 = *(const f32x4*)&hrow[k + 4];
      f32x4 h2 = *(const f32x4*)&hrow[k + 8];
      f32x4 h3 = *(const f32x4*)&hrow[k + 12];
      f32x4 w0 = *(const f32x4*)&wrow[k];
      f32x4 w1 = *(const f32x4*)&wrow[k + 4];
      f32x4 w2 = *(const f32x4*)&wrow[k + 8];
      f32x4 w3 = *(const f32x4*)&wrow[k + 12];
#pragma unroll
      for (int e = 0; e < 4; ++e) {
        l0 += h0[e] * w0[e];
        l1 += h1[e] * w1[e];
        l2 += h2[e] * w2[e];
        l3 += h3[e] * w3[e];
      }
    }
    out_lg[(size_t)pm[m0 + row] * 20 + part] = l0 + l1 + l2 + l3 + hb[part];
  }
}

// ---------------- final: out_x = LN(x + scatter(ag)/sqrt2) -------------------
__global__ __launch_bounds__(256) void outx_k(
    const float* __restrict__ x, const float* __restrict__ ag,
    const int* __restrict__ inv, const float* __restrict__ g,
    const float* __restrict__ bb, float* __restrict__ out) {
  __shared__ float red[256];
  int n = blockIdx.x, tid = threadIdx.x;
  int mi = inv[n];
  float v = x[(size_t)n * 256 + tid];
  if (mi >= 0) v += ag[(size_t)mi * 256 + tid] * RSQRT2;
  red[tid] = v;
  __syncthreads();
  for (int off = 128; off; off >>= 1) {
    if (tid < off) red[tid] += red[tid + off];
    __syncthreads();
  }
  float mean = red[0] * (1.0f / 256.0f);
  __syncthreads();
  red[tid] = v * v;
  __syncthreads();
  for (int off = 128; off; off >>= 1) {
    if (tid < off) red[tid] += red[tid + off];
    __syncthreads();
  }
  float var = red[0] * (1.0f / 256.0f) - mean * mean;
  float is = 1.0f / sqrtf(var + 1e-5f);
  out[(size_t)n * 256 + tid] = (v - mean) * is * g[tid] + bb[tid];
}

// ---------------- index compaction -------------------------------------------
__global__ void init_idx_k(int* __restrict__ list, int* __restrict__ inv,
                           int* __restrict__ cnt, int N, int B) {
  int i = blockIdx.x * 256 + threadIdx.x;
  if (i < B * N) list[i] = -1;
  if (i < N) inv[i] = -1;
  if (i < B) cnt[i] = 0;
}

__global__ void compact_k(const int* __restrict__ pm,
                          const int* __restrict__ batch, int* __restrict__ list,
                          int* __restrict__ inv, int* __restrict__ cnt, int N) {
  int m = blockIdx.x * 256 + threadIdx.x;
  if (m >= N) return;
  int p = pm[m];
  int b = batch[p];
  int slot = atomicAdd(&cnt[b], 1);
  list[(size_t)b * N + slot] = m;
  inv[p] = m;
}

// -----------------------------------------------------------------------------
extern "C" void kernel_launch(void* const* d_in, const int* in_sizes, int n_in,
                              void* d_out, int out_size, void* d_ws,
                              size_t ws_size, hipStream_t stream) {
  const float* x = (const float*)d_in[0];
  const float* emb = (const float*)d_in[1];
  const float* mask = (const float*)d_in[2];
  const int* pm = (const int*)d_in[3];
  const int* batch = (const int*)d_in[4];
  const float* Wq = (const float*)d_in[5];
  const float* Wk = (const float*)d_in[6];
  const float* Wv = (const float*)d_in[7];
  const float* ag_s = (const float*)d_in[8];
  const float* ag_b = (const float*)d_in[9];
  const float* Wag = (const float*)d_in[10];
  const float* rls = (const float*)d_in[11];
  const float* rlb = (const float*)d_in[12];
  const float* rw1 = (const float*)d_in[13];
  const float* rb1 = (const float*)d_in[14];
  const float* rw2 = (const float*)d_in[15];
  const float* rb2 = (const float*)d_in[16];
  const float* hw = (const float*)d_in[17];
  const float* hb = (const float*)d_in[18];
  const float* ens = (const float*)d_in[19];
  const float* enb = (const float*)d_in[20];

  const int N = in_sizes[0] / 256;  // 4096
  const int B = in_sizes[2] / 512;  // 4

  char* wsb = (char*)d_ws;
  // conversion-phase (dead before packed is written):
  u16* embbf = (u16*)(wsb + 0);
  u16* xbf   = (u16*)(wsb + 5242880);
  u16* Wkvbf = (u16*)(wsb + 7340032);
  u16* Wqbf  = (u16*)(wsb + 9961472);
  // attention phase:
  u16* packed = (u16*)(wsb + 0);           // 32 MB
  u16* KVbf   = (u16*)(wsb + 33554432);    // 4 MB
  u16* Qbf    = (u16*)(wsb + 37748736);    // 4 MB
  u16* VT     = (u16*)(wsb + 41943040);    // 2 MB
  u16* featE  = (u16*)(wsb + 44040192);    // 4 MB
  // post-attention:
  float* AG = (float*)(wsb + 37748736);    // over Qbf (dead after attn)
  // persistent:
  u16* Wagbf = (u16*)(wsb + 48234496);
  u16* rw1bf = (u16*)(wsb + 48496640);
  u16* rw2bf = (u16*)(wsb + 48889856);
  int* list  = (int*)(wsb + 49545216);
  int* inv   = (int*)(wsb + 49610752);
  int* cnt   = (int*)(wsb + 49627136);

  float* out_x = (float*)d_out;
  float* out_lg = out_x + (size_t)N * 256;
  float* out_sc = out_lg + (size_t)N * 20;

  // 0. conversions + index compaction
  CvtArgs ca;
  ca.d[0] = {emb, embbf, 2 * 512 * 1280 * 2};
  ca.d[1] = {x, xbf, 4096 * 256};
  ca.d[2] = {Wk, Wkvbf, 512 * 1280};
  ca.d[3] = {Wv, Wkvbf + 512 * 1280, 512 * 1280};
  ca.d[4] = {Wq, Wqbf, 512 * 256};
  ca.d[5] = {Wag, Wagbf, 256 * 512};
  ca.d[6] = {rw1, rw1bf, 3 * 256 * 256};
  ca.d[7] = {rw2, rw2bf, 3 * 256 * 256};
  cvt_k<<<dim3(1281, 1, 8), 256, 0, stream>>>(ca);
  init_idx_k<<<(B * N + 255) / 256, 256, 0, stream>>>(list, inv, cnt, N, B);
  compact_k<<<(N + 255) / 256, 256, 0, stream>>>(pm, batch, list, inv, cnt, N);

  // 1. fused K+V projection
  mgemm2<EPI_NONE, true><<<dim3(16, 16), 256, 0, stream>>>(
      embbf, Wkvbf, KVbf, B * 512, 1024, 1280, 1280, 1280, 1024,
      nullptr, nullptr, nullptr, nullptr);
  // 2. Q projection with gather
  mgemm2<EPI_NONE, true><<<dim3(8, 32), 256, 0, stream>>>(
      xbf, Wqbf, Qbf, N, 512, 256, 256, 256, 512,
      nullptr, nullptr, pm, nullptr);
  vtrans<<<dim3(16, 16, B), 256, 0, stream>>>(KVbf, VT);

  // 3. fused attention (scores+softmax+PV), then unpack for the fp32 output
  attn_fused<<<dim3(N / 32, B * 8), 256, 0, stream>>>(
      Qbf, KVbf, VT, list, mask, packed, featE, N);
  unpack_k<<<N, 256, 0, stream>>>(packed, pm, out_sc, N);

  // 4+5+6. fused LN512 + AG GEMM + residual MLP + head
  mlp_fused<<<dim3(N / 16), 512, 0, stream>>>(
      featE, ag_s, ag_b, Wagbf, AG, rls, rlb, rw1bf, rb1, rw2bf, rb2,
      hw, hb, pm, out_lg);

  // 7. final LN
  outx_k<<<N, 256, 0, stream>>>(x, AG, inv, ens, enb, out_x);
}